// Round 19
// baseline (54.983 us; speedup 1.0000x reference)
//
#include <hip/hip_runtime.h>
#include <hip/hip_bf16.h>
#include <hip/hip_fp16.h>

// HeteroSoap via MFMA: c[s*4+n][ab] = sum_atoms f_sn * Y_ab = 16x16 GEMM, K=N.
// Round 19 = round-18 with the RELEASE-FENCE BUG fixed: every thread now
// executes __threadfence() after its OWN partials/gsum store (a fence only
// orders the calling thread's writes; __syncthreads is workgroup-scope, so
// r18's thread-0-only fence let 255 threads' stores race the group reducer
// -> a few stale rows -> absmax 1.1e6).
// Structure: r17 datapath verbatim (best passing, 17.22us) + single-launch
// tail via modulo-tickets on PERSISTENT counters (exactly 16/32 increments
// per launch -> one winner for any initial value; no memset, poison-proof).
// block -> partials row (agent stores+fence); last-of-16 per group reduces
// -> gsum; last-of-32 groups reduces gsum, finalizes, writes out.

typedef float f32x4 __attribute__((ext_vector_type(4)));
typedef unsigned int uint4v __attribute__((ext_vector_type(4)));
typedef _Float16 h2 __attribute__((ext_vector_type(2)));
typedef _Float16 half8 __attribute__((ext_vector_type(8)));

#define NB 512
#define NCH 4   // fixed chunks/wave: 2048 waves * 128 atoms * 4 = 1,048,576 >= N

__global__ void __launch_bounds__(256) soap_fused(
    const float* __restrict__ coo, const int* __restrict__ numbers,
    int N, float* __restrict__ partials, float* __restrict__ gsum,
    unsigned* __restrict__ gcnt, float* __restrict__ out)
{
    __shared__ unsigned int lT[4][2][16][64];  // [wave][A|B][comp][pair] 32 KB
    __shared__ float cs[256];
    __shared__ int flag1, flag2;

    const int lane = threadIdx.x & 63;
    const int w = threadIdx.x >> 6;
    const int g = lane >> 4;            // k-group
    const int comp = lane & 15;         // fragment index dim (A row / B col)

    unsigned int* lA = &lT[w][0][0][0];
    unsigned int* lB = &lT[w][1][0][0];

    // Read offsets: MFMA m reads 4 consecutive swizzled dwords = pairs
    // 16m+4g..+3 = atoms 32m+8g .. 32m+8g+7. Same map for A and B.
    const unsigned swz = (unsigned)((comp & 7) << 2);
    const unsigned rbase = (unsigned)(comp << 6);
    unsigned rd[4];
#pragma unroll
    for (int m = 0; m < 4; ++m)
        rd[m] = rbase + ((unsigned)(16 * m + 4 * g) ^ swz);

    f32x4 acc = {0.f, 0.f, 0.f, 0.f};

    // ---- ALL loads up-front, fully contiguous: lane owns atoms (2p, 2p+1) ---
    const int wid = blockIdx.x * 4 + w;
    float X0[NCH], Y0[NCH], Z0[NCH], X1[NCH], Y1[NCH], Z1[NCH];
    int n0[NCH], n1[NCH];
#pragma unroll
    for (int k = 0; k < NCH; ++k) {
        int base = (wid + k * 2048) * 128;
        int p = base + 2 * lane;            // first atom of this lane's pair
        int pc = p < N - 1 ? p : N - 2;     // clamp pair start (N even)
        const float* cb = coo + 3 * pc;     // 3*pc even -> 8B aligned
        float2 c0 = *(const float2*)(cb);
        float2 c1 = *(const float2*)(cb + 2);
        float2 c2 = *(const float2*)(cb + 4);
        X0[k] = c0.x; Y0[k] = c0.y; Z0[k] = c1.x;
        X1[k] = c1.y; Y1[k] = c2.x; Z1[k] = c2.y;
        int2 nm = *(const int2*)(numbers + pc);   // pc even -> 8B aligned
        n0[k] = p < N ? nm.x : -1;
        n1[k] = p + 1 < N ? nm.y : -1;
    }

#pragma unroll
    for (int k = 0; k < NCH; ++k) {
        int num0 = n0[k], num1 = n1[k];

        // Radial in f32 per atom (exp-arg precision), store f16.
        float x0 = X0[k] * 0.5f, y0 = Y0[k] * 0.5f, z0 = Z0[k] * 0.5f;
        float x1 = X1[k] * 0.5f, y1 = Y1[k] * 0.5f, z1 = Z1[k] * 0.5f;
        float r20 = x0 * x0 + y0 * y0 + z0 * z0;
        float r21 = x1 * x1 + y1 * y1 + z1 * z1;
        float t0 = fmaxf(1.f - sqrtf(r20) * (1.f / 3.f), 0.f);
        float t1 = fmaxf(1.f - sqrtf(r21) * (1.f / 3.f), 0.f);
        float f00 = __expf(-0.5f * r20) * t0 * t0;
        float f01 = __expf(-0.5f * r21) * t1 * t1;

        h2 fpk[4];
        fpk[0] = (h2){(_Float16)f00, (_Float16)f01};
        fpk[1] = (h2){(_Float16)(f00 * r20), (_Float16)(f01 * r21)};
        fpk[2] = (h2){(_Float16)(f00 * r20 * r20), (_Float16)(f01 * r21 * r21)};
        fpk[3] = (h2){(_Float16)(f00 * r20 * r20 * r20), (_Float16)(f01 * r21 * r21 * r21)};

        // Species one-hot as f16 pair masks (invalid atom -> num=-1 -> 0).
        h2 msk[4];
#pragma unroll
        for (int s = 0; s < 4; ++s)
            msk[s] = (h2){(_Float16)(num0 == s ? 1.f : 0.f),
                          (_Float16)(num1 == s ? 1.f : 0.f)};

        // Packed f16 inputs for the harmonic chain (atom 2p lo, atom 2p+1 hi).
        h2 xp = (h2){(_Float16)x0, (_Float16)x1};
        h2 yp = (h2){(_Float16)y0, (_Float16)y1};
        h2 zp = (h2){(_Float16)z0, (_Float16)z1};
        h2 rp = (h2){(_Float16)r20, (_Float16)r21};

        // Solid harmonics, packed pairs (v_pk_mul/fma_f16):
        h2 re11 = (_Float16)-0.34549414947133550f * xp;
        h2 im11 = (_Float16)-0.34549414947133550f * yp;
        h2 re10 = (_Float16) 0.48860251190291992f * zp;
        h2 re22 = (_Float16)-1.11803398874989490f * (xp * re11 - yp * im11);
        h2 im22 = (_Float16)-1.11803398874989490f * (xp * im11 + yp * re11);
        h2 re21 = (_Float16) 2.23606797749978970f * (zp * re11);
        h2 im21 = (_Float16) 2.23606797749978970f * (zp * im11);
        h2 re20 = (_Float16) 1.93649167310370850f * (zp * re10 - (_Float16)0.16286750396763996f * rp);
        h2 re33 = (_Float16)-1.08012344973464350f * (xp * re22 - yp * im22);
        h2 im33 = (_Float16)-1.08012344973464350f * (xp * im22 + yp * re22);
        h2 re32 = (_Float16) 2.64575131106459070f * (zp * re22);
        h2 im32 = (_Float16) 2.64575131106459070f * (zp * im22);
        h2 re31 = (_Float16) 2.09165006633518890f * (zp * re21 - (_Float16)0.44721359549995793f * (rp * re11));
        h2 im31 = (_Float16) 2.09165006633518890f * (zp * im21 - (_Float16)0.44721359549995793f * (rp * im11));
        h2 re30 = (_Float16) 1.97202659436653870f * (zp * re20 - (_Float16)0.51639777949432220f * (rp * re10));

        h2 ypk[16];
        ypk[0] = (h2){(_Float16)0.28209479177387814f, (_Float16)0.28209479177387814f};
        ypk[1] = im11; ypk[2]  = im22; ypk[3]  = im33;
        ypk[4] = re11; ypk[5]  = re10; ypk[6]  = im21; ypk[7]  = im32;
        ypk[8] = re22; ypk[9]  = re21; ypk[10] = re20; ypk[11] = im31;
        ypk[12] = re33; ypk[13] = re32; ypk[14] = re31; ypk[15] = re30;

        // Swizzled stores: lane owns pair-column `lane`; one b32 per tile/comp.
#pragma unroll
        for (int c = 0; c < 16; ++c) {
            h2 fs = fpk[c & 3] * msk[c >> 2];
            union { h2 h; unsigned u; } ua, ub;
            ua.h = fs; ub.h = ypk[c];
            unsigned idx = (unsigned)(c << 6) + ((unsigned)lane ^ ((unsigned)(c & 7) << 2));
            lA[idx] = ua.u;
            lB[idx] = ub.u;
        }

        // 4 MFMAs (32 atoms each); wave-private tile, in-order LDS per wave.
#pragma unroll
        for (int m = 0; m < 4; ++m) {
            union { uint4v q; half8 h; } A, B;
            A.q = *(const uint4v*)&lA[rd[m]];
            B.q = *(const uint4v*)&lB[rd[m]];
            acc = __builtin_amdgcn_mfma_f32_16x16x32_f16(A.h, B.h, acc, 0, 0, 0);
        }
    }

    // C/D layout (m89): lane, reg rr -> c[i=(lane>>4)*4+rr][j=lane&15].
    // Reuse this wave's (idle, wave-private) tile as the reduce buffer.
    float* credw = (float*)&lT[w][0][0][0];
#pragma unroll
    for (int rr = 0; rr < 4; ++rr)
        credw[((lane >> 4) * 4 + rr) * 16 + (lane & 15)] = acc[rr];
    __syncthreads();

    const int tt = threadIdx.x;
    const int grp = blockIdx.x >> 4;          // 32 groups of 16 blocks
    {
        float v = ((float*)&lT[0][0][0][0])[tt] + ((float*)&lT[1][0][0][0])[tt] +
                  ((float*)&lT[2][0][0][0])[tt] + ((float*)&lT[3][0][0][0])[tt];
        __hip_atomic_store(&partials[blockIdx.x * 256 + tt], v,
                           __ATOMIC_RELAXED, __HIP_MEMORY_SCOPE_AGENT);
    }
    __threadfence();          // RELEASE by EVERY writer thread (r18 bug fix)
    __syncthreads();
    if (tt == 0) {
        unsigned old = __hip_atomic_fetch_add(&gcnt[grp], 1u,
                           __ATOMIC_ACQ_REL, __HIP_MEMORY_SCOPE_AGENT);
        flag1 = (((old + 1u) & 15u) == 0u);   // exactly 16 incr/launch ->
    }                                         // one winner for ANY init value
    __syncthreads();
    if (!flag1) return;

    // Group reducer: sum this group's 16 rows -> gsum row.
    __threadfence();                          // acquire (every reader thread)
    {
        float s = 0.f;
#pragma unroll
        for (int r = 0; r < 16; ++r)
            s += __hip_atomic_load(&partials[(grp * 16 + r) * 256 + tt],
                                   __ATOMIC_RELAXED, __HIP_MEMORY_SCOPE_AGENT);
        __hip_atomic_store(&gsum[grp * 256 + tt], s,
                           __ATOMIC_RELAXED, __HIP_MEMORY_SCOPE_AGENT);
    }
    __threadfence();          // RELEASE by every writer thread
    __syncthreads();
    if (tt == 0) {
        unsigned old = __hip_atomic_fetch_add(&gcnt[32], 1u,
                           __ATOMIC_ACQ_REL, __HIP_MEMORY_SCOPE_AGENT);
        flag2 = (((old + 1u) & 31u) == 0u);   // exactly 32 incr/launch
    }
    __syncthreads();
    if (!flag2) return;

    // Final reducer: total c, then Yr/Yi/nnl contraction.
    __threadfence();                          // acquire (every reader thread)
    {
        float s = 0.f;
#pragma unroll
        for (int gg = 0; gg < 32; ++gg)
            s += __hip_atomic_load(&gsum[gg * 256 + tt],
                                   __ATOMIC_RELAXED, __HIP_MEMORY_SCOPE_AGENT);
        cs[tt] = s;
    }
    __syncthreads();

    // p1[a,b,n,m,l] = sum_{j<=l} w_j c[b,m,l,j] c[a,n,l,j] (w=1 if j==l else 2)
    // p2[a,b,n,m,l] = sum_{i<l}  2  c[b,m,i,l] c[a,n,i,l]
    // out = (p1+p2) * nnl[n,m,l]
    const float fact[7] = {1.f, 1.f, 2.f, 6.f, 24.f, 120.f, 720.f};
#pragma unroll
    for (int k = 0; k < 4; ++k) {
        int o = k * 256 + tt;
        int l = o & 3, m = (o >> 2) & 3, n = (o >> 4) & 3,
            b = (o >> 6) & 3, a = (o >> 8) & 3;
        const float* cbm = &cs[(b * 4 + m) * 16];
        const float* can = &cs[(a * 4 + n) * 16];
        float vv = 0.f;
        for (int j = 0; j <= l; ++j) {
            float wgt = (j == l) ? 1.f : 2.f;
            vv += wgt * cbm[l * 4 + j] * can[l * 4 + j];
        }
        for (int i = 0; i < l; ++i)
            vv += 2.f * cbm[i * 4 + l] * can[i * 4 + l];
        float an = 1.0f / ((float)(2 * l + 1) * (float)(1 << (2 * n + l)) * fact[n] * fact[n + l]);
        float am = 1.0f / ((float)(2 * l + 1) * (float)(1 << (2 * m + l)) * fact[m] * fact[m + l]);
        out[o] = vv * sqrtf(an * am);
    }
}

extern "C" void kernel_launch(void* const* d_in, const int* in_sizes, int n_in,
                              void* d_out, int out_size, void* d_ws, size_t ws_size,
                              hipStream_t stream)
{
    const float* coo = (const float*)d_in[0];
    const int* numbers = (const int*)d_in[1];
    int N = in_sizes[1];                 // 1,000,000 atoms

    unsigned* gcnt = (unsigned*)d_ws;            // [33] persistent mod-tickets
    float* gsum = (float*)d_ws + 64;             // [32*256] group sums
    float* partials = (float*)d_ws + 64 + 8192;  // [NB*256] block partials
    // ws requirement: (64 + 8192 + 131072) * 4 B ~= 0.56 MB. No memset needed:
    // tickets are modulo-compared (exactly 16/32 increments per launch), data
    // buffers fully overwritten before any read.

    hipLaunchKernelGGL(soap_fused, dim3(NB), dim3(256), 0, stream,
                       coo, numbers, N, partials, gsum, gcnt, (float*)d_out);
}

// Round 20
// 17.344 us; speedup vs baseline: 3.1701x; 3.1701x over previous
//
#include <hip/hip_runtime.h>
#include <hip/hip_bf16.h>
#include <hip/hip_fp16.h>

// HeteroSoap via MFMA: c[s*4+n][ab] = sum_atoms f_sn * Y_ab = 16x16 GEMM, K=N.
// Round 20 = ROUND 17 VERBATIM (session best, 17.22us). r18/r19 proved the
// single-launch fusion is strictly worse: correct device-scope fencing +
// agent-scope (uncached) partials traffic costs ~40us vs the ~free implicit
// barrier of a second launch. Final structure:
//  - accum: 512 blocks x 4 waves; packed-f16 harmonics (2 adjacent atoms per
//    lane -> 3x float2 + 1x int2 contiguous loads, hoisted for all 4 chunks);
//    radial f32; dword LDS tile [comp][pair] (lo=f one-hot, hi=Y) XOR-swizzled
//    idx^((c&7)<<2) same on write+read; fragment = one ds_read_b128;
//    v_mfma_f32_16x16x32_f16 (same A/B atom<->k map -> k-order cancels);
//    C/D layout per m89; per-block partials row (no atomics).
//  - tail: 32-block reduce -> c_ws atomics -> last-block ticket finalize.

typedef float f32x4 __attribute__((ext_vector_type(4)));
typedef unsigned int uint4v __attribute__((ext_vector_type(4)));
typedef _Float16 h2 __attribute__((ext_vector_type(2)));
typedef _Float16 half8 __attribute__((ext_vector_type(8)));

#define NB 512
#define NCH 4   // fixed chunks/wave: 2048 waves * 128 atoms * 4 = 1,048,576 >= N

__global__ void __launch_bounds__(256) soap_accum(
    const float* __restrict__ coo, const int* __restrict__ numbers,
    int N, float* __restrict__ partials, float* __restrict__ c_ws,
    int* __restrict__ counter)
{
    __shared__ unsigned int lT[4][2][16][64];  // [wave][A|B][comp][pair] 32 KB

    // Per-launch init of fused-tail state (accum ends before reduce starts).
    if (blockIdx.x == 0) {
        if (threadIdx.x < 256) c_ws[threadIdx.x] = 0.f;
        if (threadIdx.x == 0) *counter = 0;
    }

    const int lane = threadIdx.x & 63;
    const int w = threadIdx.x >> 6;
    const int g = lane >> 4;            // k-group
    const int comp = lane & 15;         // fragment index dim (A row / B col)

    unsigned int* lA = &lT[w][0][0][0];
    unsigned int* lB = &lT[w][1][0][0];

    // Read offsets: MFMA m reads 4 consecutive swizzled dwords = pairs
    // 16m+4g..+3 = atoms 32m+8g .. 32m+8g+7. Same map for A and B.
    const unsigned swz = (unsigned)((comp & 7) << 2);
    const unsigned rbase = (unsigned)(comp << 6);
    unsigned rd[4];
#pragma unroll
    for (int m = 0; m < 4; ++m)
        rd[m] = rbase + ((unsigned)(16 * m + 4 * g) ^ swz);

    f32x4 acc = {0.f, 0.f, 0.f, 0.f};

    // ---- ALL loads up-front, fully contiguous: lane owns atoms (2p, 2p+1) ---
    const int wid = blockIdx.x * 4 + w;
    float X0[NCH], Y0[NCH], Z0[NCH], X1[NCH], Y1[NCH], Z1[NCH];
    int n0[NCH], n1[NCH];
#pragma unroll
    for (int k = 0; k < NCH; ++k) {
        int base = (wid + k * 2048) * 128;
        int p = base + 2 * lane;            // first atom of this lane's pair
        int pc = p < N - 1 ? p : N - 2;     // clamp pair start (N even)
        const float* cb = coo + 3 * pc;     // 3*pc even -> 8B aligned
        float2 c0 = *(const float2*)(cb);
        float2 c1 = *(const float2*)(cb + 2);
        float2 c2 = *(const float2*)(cb + 4);
        X0[k] = c0.x; Y0[k] = c0.y; Z0[k] = c1.x;
        X1[k] = c1.y; Y1[k] = c2.x; Z1[k] = c2.y;
        int2 nm = *(const int2*)(numbers + pc);   // pc even -> 8B aligned
        n0[k] = p < N ? nm.x : -1;
        n1[k] = p + 1 < N ? nm.y : -1;
    }

#pragma unroll
    for (int k = 0; k < NCH; ++k) {
        int num0 = n0[k], num1 = n1[k];

        // Radial in f32 per atom (exp-arg precision), store f16.
        float x0 = X0[k] * 0.5f, y0 = Y0[k] * 0.5f, z0 = Z0[k] * 0.5f;
        float x1 = X1[k] * 0.5f, y1 = Y1[k] * 0.5f, z1 = Z1[k] * 0.5f;
        float r20 = x0 * x0 + y0 * y0 + z0 * z0;
        float r21 = x1 * x1 + y1 * y1 + z1 * z1;
        float t0 = fmaxf(1.f - sqrtf(r20) * (1.f / 3.f), 0.f);
        float t1 = fmaxf(1.f - sqrtf(r21) * (1.f / 3.f), 0.f);
        float f00 = __expf(-0.5f * r20) * t0 * t0;
        float f01 = __expf(-0.5f * r21) * t1 * t1;

        h2 fpk[4];
        fpk[0] = (h2){(_Float16)f00, (_Float16)f01};
        fpk[1] = (h2){(_Float16)(f00 * r20), (_Float16)(f01 * r21)};
        fpk[2] = (h2){(_Float16)(f00 * r20 * r20), (_Float16)(f01 * r21 * r21)};
        fpk[3] = (h2){(_Float16)(f00 * r20 * r20 * r20), (_Float16)(f01 * r21 * r21 * r21)};

        // Species one-hot as f16 pair masks (invalid atom -> num=-1 -> 0).
        h2 msk[4];
#pragma unroll
        for (int s = 0; s < 4; ++s)
            msk[s] = (h2){(_Float16)(num0 == s ? 1.f : 0.f),
                          (_Float16)(num1 == s ? 1.f : 0.f)};

        // Packed f16 inputs for the harmonic chain (atom 2p lo, atom 2p+1 hi).
        h2 xp = (h2){(_Float16)x0, (_Float16)x1};
        h2 yp = (h2){(_Float16)y0, (_Float16)y1};
        h2 zp = (h2){(_Float16)z0, (_Float16)z1};
        h2 rp = (h2){(_Float16)r20, (_Float16)r21};

        // Solid harmonics, packed pairs (v_pk_mul/fma_f16):
        h2 re11 = (_Float16)-0.34549414947133550f * xp;
        h2 im11 = (_Float16)-0.34549414947133550f * yp;
        h2 re10 = (_Float16) 0.48860251190291992f * zp;
        h2 re22 = (_Float16)-1.11803398874989490f * (xp * re11 - yp * im11);
        h2 im22 = (_Float16)-1.11803398874989490f * (xp * im11 + yp * re11);
        h2 re21 = (_Float16) 2.23606797749978970f * (zp * re11);
        h2 im21 = (_Float16) 2.23606797749978970f * (zp * im11);
        h2 re20 = (_Float16) 1.93649167310370850f * (zp * re10 - (_Float16)0.16286750396763996f * rp);
        h2 re33 = (_Float16)-1.08012344973464350f * (xp * re22 - yp * im22);
        h2 im33 = (_Float16)-1.08012344973464350f * (xp * im22 + yp * re22);
        h2 re32 = (_Float16) 2.64575131106459070f * (zp * re22);
        h2 im32 = (_Float16) 2.64575131106459070f * (zp * im22);
        h2 re31 = (_Float16) 2.09165006633518890f * (zp * re21 - (_Float16)0.44721359549995793f * (rp * re11));
        h2 im31 = (_Float16) 2.09165006633518890f * (zp * im21 - (_Float16)0.44721359549995793f * (rp * im11));
        h2 re30 = (_Float16) 1.97202659436653870f * (zp * re20 - (_Float16)0.51639777949432220f * (rp * re10));

        h2 ypk[16];
        ypk[0] = (h2){(_Float16)0.28209479177387814f, (_Float16)0.28209479177387814f};
        ypk[1] = im11; ypk[2]  = im22; ypk[3]  = im33;
        ypk[4] = re11; ypk[5]  = re10; ypk[6]  = im21; ypk[7]  = im32;
        ypk[8] = re22; ypk[9]  = re21; ypk[10] = re20; ypk[11] = im31;
        ypk[12] = re33; ypk[13] = re32; ypk[14] = re31; ypk[15] = re30;

        // Swizzled stores: lane owns pair-column `lane`; one b32 per tile/comp.
#pragma unroll
        for (int c = 0; c < 16; ++c) {
            h2 fs = fpk[c & 3] * msk[c >> 2];
            union { h2 h; unsigned u; } ua, ub;
            ua.h = fs; ub.h = ypk[c];
            unsigned idx = (unsigned)(c << 6) + ((unsigned)lane ^ ((unsigned)(c & 7) << 2));
            lA[idx] = ua.u;
            lB[idx] = ub.u;
        }

        // 4 MFMAs (32 atoms each); wave-private tile, in-order LDS per wave.
#pragma unroll
        for (int m = 0; m < 4; ++m) {
            union { uint4v q; half8 h; } A, B;
            A.q = *(const uint4v*)&lA[rd[m]];
            B.q = *(const uint4v*)&lB[rd[m]];
            acc = __builtin_amdgcn_mfma_f32_16x16x32_f16(A.h, B.h, acc, 0, 0, 0);
        }
    }

    // C/D layout (m89): lane, reg rr -> c[i=(lane>>4)*4+rr][j=lane&15].
    // Reuse this wave's (idle, wave-private) tile as the reduce buffer.
    float* credw = (float*)&lT[w][0][0][0];
#pragma unroll
    for (int rr = 0; rr < 4; ++rr)
        credw[((lane >> 4) * 4 + rr) * 16 + (lane & 15)] = acc[rr];
    __syncthreads();

    int tt = threadIdx.x;
    partials[blockIdx.x * 256 + tt] =
        ((float*)&lT[0][0][0][0])[tt] + ((float*)&lT[1][0][0][0])[tt] +
        ((float*)&lT[2][0][0][0])[tt] + ((float*)&lT[3][0][0][0])[tt];
}

// Fused reduce + finalize, 32 blocks. Each block sums its slice of partials
// into c_ws atomically; last block to finish does the Yr/Yi/nnl contraction.
__global__ void __launch_bounds__(256) soap_reduce_final(
    const float* __restrict__ partials, float* __restrict__ c_ws,
    int* __restrict__ counter, float* __restrict__ out)
{
    __shared__ float cs[256];
    __shared__ int lastflag;
    int t = threadIdx.x;

    float v = 0.f;
    for (int r = blockIdx.x; r < NB; r += 32)
        v += partials[r * 256 + t];           // coalesced, 16 iters
    atomicAdd(&c_ws[t], v);                   // 32 adds/address, device scope
    __syncthreads();
    if (t == 0) {
        __threadfence();                      // release our adds
        lastflag = (atomicAdd(counter, 1) == 31);
    }
    __syncthreads();
    if (!lastflag) return;

    __threadfence();                          // acquire other blocks' adds
    cs[t] = __hip_atomic_load(&c_ws[t], __ATOMIC_RELAXED,
                              __HIP_MEMORY_SCOPE_AGENT);  // L1-bypassing load
    __syncthreads();

    // p1[a,b,n,m,l] = sum_{j<=l} w_j c[b,m,l,j] c[a,n,l,j] (w=1 if j==l else 2)
    // p2[a,b,n,m,l] = sum_{i<l}  2  c[b,m,i,l] c[a,n,i,l]
    // out = (p1+p2) * nnl[n,m,l]
    const float fact[7] = {1.f, 1.f, 2.f, 6.f, 24.f, 120.f, 720.f};
#pragma unroll
    for (int k = 0; k < 4; ++k) {
        int o = k * 256 + t;
        int l = o & 3, m = (o >> 2) & 3, n = (o >> 4) & 3,
            b = (o >> 6) & 3, a = (o >> 8) & 3;
        const float* cbm = &cs[(b * 4 + m) * 16];
        const float* can = &cs[(a * 4 + n) * 16];
        float vv = 0.f;
        for (int j = 0; j <= l; ++j) {
            float wgt = (j == l) ? 1.f : 2.f;
            vv += wgt * cbm[l * 4 + j] * can[l * 4 + j];
        }
        for (int i = 0; i < l; ++i)
            vv += 2.f * cbm[i * 4 + l] * can[i * 4 + l];
        float an = 1.0f / ((float)(2 * l + 1) * (float)(1 << (2 * n + l)) * fact[n] * fact[n + l]);
        float am = 1.0f / ((float)(2 * l + 1) * (float)(1 << (2 * m + l)) * fact[m] * fact[m + l]);
        out[o] = vv * sqrtf(an * am);
    }
}

extern "C" void kernel_launch(void* const* d_in, const int* in_sizes, int n_in,
                              void* d_out, int out_size, void* d_ws, size_t ws_size,
                              hipStream_t stream)
{
    const float* coo = (const float*)d_in[0];
    const int* numbers = (const int*)d_in[1];
    int N = in_sizes[1];                 // 1,000,000 atoms

    float* c_ws = (float*)d_ws;          // [256] accumulated c
    int* counter = (int*)((float*)d_ws + 256);  // ticket counter
    float* partials = (float*)d_ws + 512;       // [NB*256] stage-1 partials
    // ws requirement: (512 + 131072) * 4 B ~= 0.53 MB.

    hipLaunchKernelGGL(soap_accum, dim3(NB), dim3(256), 0, stream,
                       coo, numbers, N, partials, c_ws, counter);
    hipLaunchKernelGGL(soap_reduce_final, dim3(32), dim3(256), 0, stream,
                       partials, c_ws, counter, (float*)d_out);
}